// Round 10
// baseline (63.912 us; speedup 1.0000x reference)
//
#include <hip/hip_runtime.h>
#include <math.h>

#define BATCH 64
#define H 512
#define W 512
#define KRAD 15
#define STRIP 64               // output rows per block
#define NSTRIP (H / STRIP)     // 8 strips per image
#define GROUP 16               // rows per barrier pair (2 scan rows per wave)
#define RING 48                // LDS ring slots; live range per group = 47

__device__ __forceinline__ float wave_reduce(float v) {
    #pragma unroll
    for (int off = 32; off > 0; off >>= 1) v += __shfl_xor(v, off);
    return v;
}

// f32 -> bf16 bits (round-to-nearest-even)
__device__ __forceinline__ unsigned bf16b(float f) {
    unsigned u = __float_as_uint(f);
    return (u + 0x7FFFu + ((u >> 16) & 1u)) >> 16;
}
__device__ __forceinline__ float fbf16(unsigned short s) {
    return __uint_as_float(((unsigned)s) << 16);
}

__device__ __forceinline__ void load_row(const float* __restrict__ base, int r, int lane,
                                         float4& a, float4& b) {
    if (0 <= r && r < H) {
        const float4* p4 = reinterpret_cast<const float4*>(base + (size_t)r * W + lane * 8);
        a = p4[0]; b = p4[1];
    } else {
        a = make_float4(0.f, 0.f, 0.f, 0.f);
        b = a;
    }
}

// TWO independent 31-wide horizontal box sums, interleaved for ILP on the
// serial shuffle chain. Each bf16-packed to its own LDS row.
__device__ __forceinline__ void scan_store2(const float4 a[2], const float4 b[2],
                                            int lane,
                                            unsigned short* dst0, unsigned short* dst1) {
    float v[2][8], P[2][8], run[2], scan[2];
    #pragma unroll
    for (int r = 0; r < 2; ++r) {
        v[r][0] = a[r].x; v[r][1] = a[r].y; v[r][2] = a[r].z; v[r][3] = a[r].w;
        v[r][4] = b[r].x; v[r][5] = b[r].y; v[r][6] = b[r].z; v[r][7] = b[r].w;
        run[r] = 0.f;
        #pragma unroll
        for (int k = 0; k < 8; ++k) { run[r] += v[r][k]; P[r][k] = run[r]; }
        scan[r] = run[r];
    }
    #pragma unroll
    for (int off = 1; off < 64; off <<= 1) {
        float n0 = __shfl_up(scan[0], off);
        float n1 = __shfl_up(scan[1], off);
        if (lane >= off) { scan[0] += n0; scan[1] += n1; }
    }
    float total[2];
    #pragma unroll
    for (int r = 0; r < 2; ++r) {
        const float excl = scan[r] - run[r];
        #pragma unroll
        for (int k = 0; k < 8; ++k) P[r][k] += excl;
        total[r] = __shfl(P[r][7], 63);
    }
    // out[x] = P[min(x+15,511)] - (x>=16 ? P[x-16] : 0)
    const int xb = lane * 8;
    unsigned short* dsts[2] = {dst0, dst1};
    #pragma unroll
    for (int r = 0; r < 2; ++r) {
        float shA[8], shB[8];
        shA[0] = __shfl_down(P[r][7], 1);
        #pragma unroll
        for (int k = 1; k < 8; ++k) shA[k] = __shfl_down(P[r][k - 1], 2);
        #pragma unroll
        for (int k = 0; k < 8; ++k) shB[k] = __shfl_up(P[r][k], 2);
        float o[8];
        #pragma unroll
        for (int k = 0; k < 8; ++k) {
            const int x = xb + k;
            const float A  = (x + KRAD <= W - 1) ? shA[k] : total[r];
            const float Bv = (x >= KRAD + 1) ? shB[k] : 0.f;
            o[k] = A - Bv;
        }
        uint4 wv;
        wv.x = bf16b(o[0]) | (bf16b(o[1]) << 16);
        wv.y = bf16b(o[2]) | (bf16b(o[3]) << 16);
        wv.z = bf16b(o[4]) | (bf16b(o[5]) << 16);
        wv.w = bf16b(o[6]) | (bf16b(o[7]) << 16);
        *reinterpret_cast<uint4*>(dsts[r] + xb) = wv;
    }
}

// Single-row variant for the prologue.
__device__ __forceinline__ void scan_row(const float* __restrict__ img_base, int r,
                                         int lane, unsigned short* dst) {
    float4 la, lb;
    load_row(img_base, r, lane, la, lb);
    float v[8] = {la.x, la.y, la.z, la.w, lb.x, lb.y, lb.z, lb.w};
    float P[8];
    float run = 0.f;
    #pragma unroll
    for (int k = 0; k < 8; ++k) { run += v[k]; P[k] = run; }
    float scan = run;
    #pragma unroll
    for (int off = 1; off < 64; off <<= 1) {
        float n = __shfl_up(scan, off);
        if (lane >= off) scan += n;
    }
    const float excl = scan - run;
    #pragma unroll
    for (int k = 0; k < 8; ++k) P[k] += excl;
    const float total = __shfl(P[7], 63);
    float shA[8], shB[8];
    shA[0] = __shfl_down(P[7], 1);
    #pragma unroll
    for (int k = 1; k < 8; ++k) shA[k] = __shfl_down(P[k - 1], 2);
    #pragma unroll
    for (int k = 0; k < 8; ++k) shB[k] = __shfl_up(P[k], 2);
    const int xb = lane * 8;
    float o[8];
    #pragma unroll
    for (int k = 0; k < 8; ++k) {
        const int x = xb + k;
        const float A  = (x + KRAD <= W - 1) ? shA[k] : total;
        const float Bv = (x >= KRAD + 1) ? shB[k] : 0.f;
        o[k] = A - Bv;
    }
    uint4 wv;
    wv.x = bf16b(o[0]) | (bf16b(o[1]) << 16);
    wv.y = bf16b(o[2]) | (bf16b(o[3]) << 16);
    wv.z = bf16b(o[4]) | (bf16b(o[5]) << 16);
    wv.w = bf16b(o[6]) | (bf16b(o[7]) << 16);
    *reinterpret_cast<uint4*>(dst + xb) = wv;
}

// -------- Fused: horizontal scan -> 48-slot bf16 LDS ring -> vertical window + loss.
// GROUP=16 rows per barrier pair: each wave scans TWO rows in phase A (ILP on
// the shuffle chain), barrier count per block halves vs GROUP=8.
// Slot bases (offset = row - r0 + 16, mod 48):
//   sB = 16g % 48 in {0,16,32}; subv slot sB+8h+i <= 47 -> never wraps.
//   sA = (16g+31) % 48; store/addv slot sA+j (j<=15) -> one cond-sub.
__global__ __launch_bounds__(512) void fused_kernel(const float* __restrict__ pred,
                                                    const float* __restrict__ mask,
                                                    float2* __restrict__ partials) {
    __shared__ unsigned short ring[RING][W];             // 49152 B

    const int tid  = threadIdx.x;
    const int wave = tid >> 6;
    const int lane = tid & 63;
    const int img   = blockIdx.x >> 3;                   // NSTRIP = 8
    const int strip = blockIdx.x & 7;
    const int r0 = strip * STRIP;
    const int c  = tid;
    const float* mk = mask + (size_t)img * (H * W);
    const float* pr = pred + (size_t)img * (H * W);

    // Prologue: fill slots 0..30 (rows r0-16 .. r0+14)
    #pragma unroll
    for (int gp = 0; gp < 4; ++gp) {
        const int idx = gp * 8 + wave;
        if (idx < 31) scan_row(mk, r0 - 16 + idx, lane, &ring[idx][0]);
    }
    __syncthreads();

    // Initial vertical sum: slots 1..30 (rows r0-15 .. r0+14)
    float vsum = 0.f;
    #pragma unroll
    for (int s = 1; s <= 30; ++s) vsum += fbf16(ring[s][c]);

    float s0 = 0.f, s1 = 0.f;
    const float inv_k2 = 1.0f / 961.0f;
    int sA = 31;   // (16g+31) % 48
    int sB = 0;    //  16g     % 48

    for (int g = 0; g < STRIP / GROUP; ++g) {
        const int ybase = r0 + GROUP * g;

        // Phase A: scan rows ybase+15+wave and ybase+23+wave
        {
            float4 a[2], b[2];
            load_row(mk, ybase + 15 + wave, lane, a[0], b[0]);
            load_row(mk, ybase + 23 + wave, lane, a[1], b[1]);
            int w0 = sA + wave;     if (w0 >= RING) w0 -= RING;
            int w1 = sA + 8 + wave; if (w1 >= RING) w1 -= RING;
            scan_store2(a, b, lane, &ring[w0][0], &ring[w1][0]);
        }
        __syncthreads();

        // Phase B: 16 rows in two 8-row sub-chunks (register arrays stay 8-wide)
        #pragma unroll
        for (int h = 0; h < 2; ++h) {
            float addv[8], subv[8], m[8], p[8];
            #pragma unroll
            for (int i = 0; i < 8; ++i) {
                int slotA = sA + 8 * h + i;
                if (slotA >= RING) slotA -= RING;
                addv[i] = fbf16(ring[slotA][c]);
                subv[i] = fbf16(ring[sB + 8 * h + i][c]);   // <= 47, never wraps
            }
            #pragma unroll
            for (int i = 0; i < 8; ++i) {
                const int y = ybase + 8 * h + i;
                m[i] = mk[(size_t)y * W + c];
                p[i] = pr[(size_t)y * W + c];
            }
            #pragma unroll
            for (int i = 0; i < 8; ++i) {
                vsum += addv[i] - subv[i];                   // window [y-15, y+15]
                const float avg = vsum * inv_k2;
                const float w = 1.0f + 5.0f * fabsf(avg - m[i]);
                const float e = __expf(-fabsf(p[i]));
                const float softplus = __logf(1.0f + e);     // log1p(e), e in (0,1]
                const float bce = fmaxf(p[i], 0.0f) - p[i] * m[i] + softplus;
                const float r1pe = __builtin_amdgcn_rcpf(1.0f + e);
                const float sig = (p[i] >= 0.0f) ? r1pe : e * r1pe;
                const float inter = sig * m[i];
                const float denom = sig + m[i] - inter + 1.0f;  // union - inter + 1
                const float iou = 1.0f - (inter + 1.0f) * __builtin_amdgcn_rcpf(denom);
                s0 += w;
                s1 += w * (bce + iou);
            }
        }
        sA += GROUP; if (sA >= RING) sA -= RING;
        sB += GROUP; if (sB >= RING) sB -= RING;
        __syncthreads();   // ring slots free to overwrite next group
    }

    s0 = wave_reduce(s0);
    s1 = wave_reduce(s1);
    float2* wacc = reinterpret_cast<float2*>(&ring[0][0]);   // alias: ring dead now
    if (lane == 0) wacc[wave] = make_float2(s0, s1);
    __syncthreads();
    if (tid == 0) {
        float a0 = 0.f, a1 = 0.f;
        #pragma unroll
        for (int i = 0; i < 8; ++i) { a0 += wacc[i].x; a1 += wacc[i].y; }
        partials[blockIdx.x] = make_float2(a0, a1);
    }
}

// -------- Finalize: per-image ratio, mean over 64 images. One wave.
__global__ void finalize_kernel(const float2* __restrict__ partials,
                                float* __restrict__ out) {
    const int lane = threadIdx.x;   // 64 threads, one per image
    float s0 = 0.f, s1 = 0.f;
    #pragma unroll
    for (int j = 0; j < NSTRIP; ++j) {
        const float2 pp = partials[lane * NSTRIP + j];
        s0 += pp.x; s1 += pp.y;
    }
    float q = s1 / s0;
    q = wave_reduce(q);
    if (lane == 0) out[0] = q * (1.0f / (float)BATCH);
}

extern "C" void kernel_launch(void* const* d_in, const int* in_sizes, int n_in,
                              void* d_out, int out_size, void* d_ws, size_t ws_size,
                              hipStream_t stream) {
    const float* pred = (const float*)d_in[0];
    const float* mask = (const float*)d_in[1];
    float2* partials = (float2*)d_ws;   // 512 * 8B

    hipLaunchKernelGGL(fused_kernel, dim3(BATCH * NSTRIP), dim3(512), 0, stream,
                       pred, mask, partials);
    hipLaunchKernelGGL(finalize_kernel, dim3(1), dim3(64), 0, stream,
                       partials, (float*)d_out);
}

// Round 11
// 44.198 us; speedup vs baseline: 1.4460x; 1.4460x over previous
//
#include <hip/hip_runtime.h>
#include <math.h>

#define BATCH 64
#define H 512
#define W 512
#define KRAD 15
#define STRIP 64               // output rows per block
#define NSTRIP (H / STRIP)     // 8 strips per image
#define RING 48                // LDS ring slots; live span/group = 39, +8 write-ahead = 47 <= 48
                               // -> single barrier per group is race-free (see loop comment)

__device__ __forceinline__ float wave_reduce(float v) {
    #pragma unroll
    for (int off = 32; off > 0; off >>= 1) v += __shfl_xor(v, off);
    return v;
}

// f32 -> bf16 bits (round-to-nearest-even)
__device__ __forceinline__ unsigned bf16b(float f) {
    unsigned u = __float_as_uint(f);
    return (u + 0x7FFFu + ((u >> 16) & 1u)) >> 16;
}
__device__ __forceinline__ float fbf16(unsigned short s) {
    return __uint_as_float(((unsigned)s) << 16);
}

// One wave: load mask row r (zero-padded outside [0,H)), 31-wide horizontal
// box sum via register scan, bf16-pack into ring row dst.
__device__ __forceinline__ void scan_row(const float* __restrict__ img_base, int r,
                                         int lane, unsigned short* dst) {
    float o[8];
    if (0 <= r && r < H) {
        const float4* in4 = reinterpret_cast<const float4*>(img_base + (size_t)r * W + lane * 8);
        float4 va = in4[0], vb = in4[1];
        float v[8] = {va.x, va.y, va.z, va.w, vb.x, vb.y, vb.z, vb.w};
        float P[8];
        float run = 0.f;
        #pragma unroll
        for (int k = 0; k < 8; ++k) { run += v[k]; P[k] = run; }
        float scan = run;
        #pragma unroll
        for (int off = 1; off < 64; off <<= 1) {
            float n = __shfl_up(scan, off);
            if (lane >= off) scan += n;
        }
        const float excl = scan - run;
        #pragma unroll
        for (int k = 0; k < 8; ++k) P[k] += excl;        // inclusive prefix at x=8*lane+k
        const float total = __shfl(P[7], 63);
        // out[x] = P[min(x+15,511)] - (x>=16 ? P[x-16] : 0)
        float shA[8], shB[8];
        shA[0] = __shfl_down(P[7], 1);
        #pragma unroll
        for (int k = 1; k < 8; ++k) shA[k] = __shfl_down(P[k - 1], 2);
        #pragma unroll
        for (int k = 0; k < 8; ++k) shB[k] = __shfl_up(P[k], 2);
        const int xb = lane * 8;
        #pragma unroll
        for (int k = 0; k < 8; ++k) {
            const int x = xb + k;
            const float A  = (x + KRAD <= W - 1) ? shA[k] : total;
            const float Bv = (x >= KRAD + 1) ? shB[k] : 0.f;
            o[k] = A - Bv;
        }
    } else {
        #pragma unroll
        for (int k = 0; k < 8; ++k) o[k] = 0.f;
    }
    uint4 wv;
    wv.x = bf16b(o[0]) | (bf16b(o[1]) << 16);
    wv.y = bf16b(o[2]) | (bf16b(o[3]) << 16);
    wv.z = bf16b(o[4]) | (bf16b(o[5]) << 16);
    wv.w = bf16b(o[6]) | (bf16b(o[7]) << 16);
    *reinterpret_cast<uint4*>(dst + lane * 8) = wv;      // 16B, conflict-free
}

// -------- Fused: horizontal scan -> 48-slot bf16 LDS ring -> vertical window + loss.
// ONE barrier per 8-row group. Safety: during group g's phase B, the only writes
// that can be concurrently in flight are group g+1's phase-A stores (any wave
// further ahead blocks at g+1's barrier). Those land at slots (8g+39..8g+46) mod 48,
// disjoint from g's read slots {8g..8g+7} and {8g+31..8g+38} mod 48.
//   sB = 8g % 48     (subv base), sB+i <= 47 -> never wraps
//   sA = (8g+31)%48  (store/addv base), sA+k <= 54 -> one cond-sub
__global__ __launch_bounds__(512) void fused_kernel(const float* __restrict__ pred,
                                                    const float* __restrict__ mask,
                                                    float2* __restrict__ partials) {
    __shared__ unsigned short ring[RING][W];             // 49152 B

    const int tid  = threadIdx.x;
    const int wave = tid >> 6;
    const int lane = tid & 63;
    const int img   = blockIdx.x >> 3;                   // NSTRIP = 8
    const int strip = blockIdx.x & 7;
    const int r0 = strip * STRIP;
    const int c  = tid;
    const float* mk = mask + (size_t)img * (H * W);
    const float* pr = pred + (size_t)img * (H * W);

    // Prologue: fill slots 0..30 (rows r0-16 .. r0+14)
    #pragma unroll
    for (int gp = 0; gp < 4; ++gp) {
        const int idx = gp * 8 + wave;
        if (idx < 31) scan_row(mk, r0 - 16 + idx, lane, &ring[idx][0]);
    }
    __syncthreads();

    // Initial vertical sum: slots 1..30 (rows r0-15 .. r0+14)
    float vsum = 0.f;
    #pragma unroll
    for (int s = 1; s <= 30; ++s) vsum += fbf16(ring[s][c]);

    float s0 = 0.f, s1 = 0.f;
    const float inv_k2 = 1.0f / 961.0f;
    int sA = 31;   // (8g+31) % 48
    int sB = 0;    //  8g     % 48

    for (int g = 0; g < STRIP / 8; ++g) {
        const int ybase = r0 + 8 * g;
        // Phase A: scan row ybase+15+wave into slot (sA+wave) mod 48
        {
            int slot = sA + wave;
            if (slot >= RING) slot -= RING;
            scan_row(mk, ybase + 15 + wave, lane, &ring[slot][0]);
        }
        __syncthreads();   // the ONLY barrier per group

        // Phase B: issue global m/p loads first (latency hides under LDS+math)
        float m[8], p[8];
        #pragma unroll
        for (int i = 0; i < 8; ++i) {
            const int y = ybase + i;
            m[i] = mk[(size_t)y * W + c];
            p[i] = pr[(size_t)y * W + c];
        }
        float addv[8], subv[8];
        #pragma unroll
        for (int i = 0; i < 8; ++i) {
            int slotA = sA + i;
            if (slotA >= RING) slotA -= RING;
            addv[i] = fbf16(ring[slotA][c]);
            subv[i] = fbf16(ring[sB + i][c]);            // sB+i <= 47, never wraps
        }
        #pragma unroll
        for (int i = 0; i < 8; ++i) {
            vsum += addv[i] - subv[i];                   // window [y-15, y+15]
            const float avg = vsum * inv_k2;
            const float w = 1.0f + 5.0f * fabsf(avg - m[i]);
            const float e = __expf(-fabsf(p[i]));
            const float softplus = __logf(1.0f + e);     // log1p(e), e in (0,1]
            const float bce = fmaxf(p[i], 0.0f) - p[i] * m[i] + softplus;
            const float r1pe = __builtin_amdgcn_rcpf(1.0f + e);
            const float sig = (p[i] >= 0.0f) ? r1pe : e * r1pe;
            const float inter = sig * m[i];
            const float denom = sig + m[i] - inter + 1.0f;  // union - inter + 1
            const float iou = 1.0f - (inter + 1.0f) * __builtin_amdgcn_rcpf(denom);
            s0 += w;
            s1 += w * (bce + iou);
        }
        sA += 8; if (sA >= RING) sA -= RING;
        sB += 8; if (sB >= RING) sB -= RING;
        // no tail barrier: RING=48 slack covers the one-group write-ahead
    }

    s0 = wave_reduce(s0);
    s1 = wave_reduce(s1);
    __syncthreads();                                     // all ring reads done
    float2* wacc = reinterpret_cast<float2*>(&ring[0][0]);   // alias: ring dead now
    if (lane == 0) wacc[wave] = make_float2(s0, s1);
    __syncthreads();
    if (tid == 0) {
        float a0 = 0.f, a1 = 0.f;
        #pragma unroll
        for (int i = 0; i < 8; ++i) { a0 += wacc[i].x; a1 += wacc[i].y; }
        partials[blockIdx.x] = make_float2(a0, a1);
    }
}

// -------- Finalize: per-image ratio, mean over 64 images. One wave.
__global__ void finalize_kernel(const float2* __restrict__ partials,
                                float* __restrict__ out) {
    const int lane = threadIdx.x;   // 64 threads, one per image
    float s0 = 0.f, s1 = 0.f;
    #pragma unroll
    for (int j = 0; j < NSTRIP; ++j) {
        const float2 pp = partials[lane * NSTRIP + j];
        s0 += pp.x; s1 += pp.y;
    }
    float q = s1 / s0;
    q = wave_reduce(q);
    if (lane == 0) out[0] = q * (1.0f / (float)BATCH);
}

extern "C" void kernel_launch(void* const* d_in, const int* in_sizes, int n_in,
                              void* d_out, int out_size, void* d_ws, size_t ws_size,
                              hipStream_t stream) {
    const float* pred = (const float*)d_in[0];
    const float* mask = (const float*)d_in[1];
    float2* partials = (float2*)d_ws;   // 512 * 8B

    hipLaunchKernelGGL(fused_kernel, dim3(BATCH * NSTRIP), dim3(512), 0, stream,
                       pred, mask, partials);
    hipLaunchKernelGGL(finalize_kernel, dim3(1), dim3(64), 0, stream,
                       partials, (float*)d_out);
}

// Round 12
// 42.087 us; speedup vs baseline: 1.5186x; 1.0502x over previous
//
#include <hip/hip_runtime.h>
#include <math.h>

#define BATCH 64
#define H 512
#define W 512
#define KRAD 15
#define STRIP 64               // output rows per block
#define NSTRIP (H / STRIP)     // 8 strips per image
#define RING 48                // LDS ring slots; live span/group = 39, +8 write-ahead = 47 <= 48

__device__ __forceinline__ float wave_reduce(float v) {
    #pragma unroll
    for (int off = 32; off > 0; off >>= 1) v += __shfl_xor(v, off);
    return v;
}

// f32 -> bf16 bits (round-to-nearest-even)
__device__ __forceinline__ unsigned bf16b(float f) {
    unsigned u = __float_as_uint(f);
    return (u + 0x7FFFu + ((u >> 16) & 1u)) >> 16;
}
__device__ __forceinline__ float fbf16(unsigned short s) {
    return __uint_as_float(((unsigned)s) << 16);
}

// One wave: 31-wide horizontal box sum of mask row r (zero padded), bf16-pack
// into ring row dst. CHAIN-FREE formulation: lane L owns x in [8L, 8L+8);
//   out[k] = suffix_{L-2}(k+1) + T_{L-1} + T_L + T_{L+1} + prefix_{L+2}(k-1)
// All 17 shuffles are independent (no serial wave-scan). Edge lanes masked to 0
// reproduce zero-padding exactly (end-clip at x=511 likewise).
__device__ __forceinline__ void scan_row(const float* __restrict__ img_base, int r,
                                         int lane, unsigned short* dst) {
    float o[8];
    if (0 <= r && r < H) {
        const float4* in4 = reinterpret_cast<const float4*>(img_base + (size_t)r * W + lane * 8);
        float4 va = in4[0], vb = in4[1];
        float v[8] = {va.x, va.y, va.z, va.w, vb.x, vb.y, vb.z, vb.w};
        // local inclusive prefix; P[7] = lane total T
        float P[8];
        P[0] = v[0];
        #pragma unroll
        for (int k = 1; k < 8; ++k) P[k] = P[k - 1] + v[k];
        const float T = P[7];

        // independent neighbor shuffles
        float Tm1 = __shfl_up(T, 1);
        float Tm2 = __shfl_up(T, 2);
        float Tp1 = __shfl_down(T, 1);
        float Pm2[7], Pp2[7];
        #pragma unroll
        for (int k = 0; k < 7; ++k) Pm2[k] = __shfl_up(P[k], 2);
        #pragma unroll
        for (int k = 0; k < 7; ++k) Pp2[k] = __shfl_down(P[k], 2);

        // boundary masks (zero-padding semantics)
        if (lane < 1) Tm1 = 0.f;
        if (lane < 2) { Tm2 = 0.f; }
        if (lane > 62) Tp1 = 0.f;
        if (lane < 2) {
            #pragma unroll
            for (int k = 0; k < 7; ++k) Pm2[k] = 0.f;
        }
        if (lane > 61) {
            #pragma unroll
            for (int k = 0; k < 7; ++k) Pp2[k] = 0.f;
        }

        const float C = Tm1 + T + Tp1;
        o[0] = C + (Tm2 - Pm2[0]);
        #pragma unroll
        for (int k = 1; k < 7; ++k) o[k] = C + (Tm2 - Pm2[k]) + Pp2[k - 1];
        o[7] = C + Pp2[6];
    } else {
        #pragma unroll
        for (int k = 0; k < 8; ++k) o[k] = 0.f;
    }
    uint4 wv;
    wv.x = bf16b(o[0]) | (bf16b(o[1]) << 16);
    wv.y = bf16b(o[2]) | (bf16b(o[3]) << 16);
    wv.z = bf16b(o[4]) | (bf16b(o[5]) << 16);
    wv.w = bf16b(o[6]) | (bf16b(o[7]) << 16);
    *reinterpret_cast<uint4*>(dst + lane * 8) = wv;      // 16B, conflict-free
}

// -------- Fused: chain-free scan -> 48-slot bf16 LDS ring -> vertical window + loss.
// ONE barrier per 8-row group (write-ahead slots disjoint; see R11 analysis):
// during group g's phase B only group g+1's stores can be in flight; they land at
// slots (8g+39..8g+46) mod 48, disjoint from g's reads {8g..8g+7, 8g+31..8g+38}.
__global__ __launch_bounds__(512) void fused_kernel(const float* __restrict__ pred,
                                                    const float* __restrict__ mask,
                                                    float2* __restrict__ partials) {
    __shared__ unsigned short ring[RING][W];             // 49152 B

    const int tid  = threadIdx.x;
    const int wave = tid >> 6;
    const int lane = tid & 63;
    const int img   = blockIdx.x >> 3;                   // NSTRIP = 8
    const int strip = blockIdx.x & 7;
    const int r0 = strip * STRIP;
    const int c  = tid;
    const float* mk = mask + (size_t)img * (H * W);
    const float* pr = pred + (size_t)img * (H * W);

    // Prologue: fill slots 0..30 (rows r0-16 .. r0+14)
    #pragma unroll
    for (int gp = 0; gp < 4; ++gp) {
        const int idx = gp * 8 + wave;
        if (idx < 31) scan_row(mk, r0 - 16 + idx, lane, &ring[idx][0]);
    }
    __syncthreads();

    // Initial vertical sum: slots 1..30 (rows r0-15 .. r0+14)
    float vsum = 0.f;
    #pragma unroll
    for (int s = 1; s <= 30; ++s) vsum += fbf16(ring[s][c]);

    float s0 = 0.f, s1 = 0.f;
    const float inv_k2 = 1.0f / 961.0f;
    int sA = 31;   // (8g+31) % 48
    int sB = 0;    //  8g     % 48

    for (int g = 0; g < STRIP / 8; ++g) {
        const int ybase = r0 + 8 * g;
        // Phase A: scan row ybase+15+wave into slot (sA+wave) mod 48
        {
            int slot = sA + wave;
            if (slot >= RING) slot -= RING;
            scan_row(mk, ybase + 15 + wave, lane, &ring[slot][0]);
        }
        __syncthreads();   // the ONLY barrier per group

        // Phase B: issue global m/p loads first (latency hides under LDS+math)
        float m[8], p[8];
        #pragma unroll
        for (int i = 0; i < 8; ++i) {
            const int y = ybase + i;
            m[i] = mk[(size_t)y * W + c];
            p[i] = pr[(size_t)y * W + c];
        }
        float addv[8], subv[8];
        #pragma unroll
        for (int i = 0; i < 8; ++i) {
            int slotA = sA + i;
            if (slotA >= RING) slotA -= RING;
            addv[i] = fbf16(ring[slotA][c]);
            subv[i] = fbf16(ring[sB + i][c]);            // sB+i <= 47, never wraps
        }
        // window sums first (short serial chain), then 8 independent math bodies
        float ws[8];
        {
            float acc = vsum;
            #pragma unroll
            for (int i = 0; i < 8; ++i) { acc += addv[i] - subv[i]; ws[i] = acc; }
            vsum = acc;
        }
        #pragma unroll
        for (int i = 0; i < 8; ++i) {
            const float avg = ws[i] * inv_k2;
            const float w = 1.0f + 5.0f * fabsf(avg - m[i]);
            const float e = __expf(-fabsf(p[i]));
            const float softplus = __logf(1.0f + e);     // log1p(e), e in (0,1]
            const float bce = fmaxf(p[i], 0.0f) - p[i] * m[i] + softplus;
            const float r1pe = __builtin_amdgcn_rcpf(1.0f + e);
            const float sig = (p[i] >= 0.0f) ? r1pe : e * r1pe;
            const float inter = sig * m[i];
            const float denom = sig + m[i] - inter + 1.0f;  // union - inter + 1
            const float iou = 1.0f - (inter + 1.0f) * __builtin_amdgcn_rcpf(denom);
            s0 += w;
            s1 += w * (bce + iou);
        }
        sA += 8; if (sA >= RING) sA -= RING;
        sB += 8; if (sB >= RING) sB -= RING;
        // no tail barrier: RING=48 slack covers the one-group write-ahead
    }

    s0 = wave_reduce(s0);
    s1 = wave_reduce(s1);
    __syncthreads();                                     // all ring reads done
    float2* wacc = reinterpret_cast<float2*>(&ring[0][0]);   // alias: ring dead now
    if (lane == 0) wacc[wave] = make_float2(s0, s1);
    __syncthreads();
    if (tid == 0) {
        float a0 = 0.f, a1 = 0.f;
        #pragma unroll
        for (int i = 0; i < 8; ++i) { a0 += wacc[i].x; a1 += wacc[i].y; }
        partials[blockIdx.x] = make_float2(a0, a1);
    }
}

// -------- Finalize: per-image ratio, mean over 64 images. One wave.
__global__ void finalize_kernel(const float2* __restrict__ partials,
                                float* __restrict__ out) {
    const int lane = threadIdx.x;   // 64 threads, one per image
    float s0 = 0.f, s1 = 0.f;
    #pragma unroll
    for (int j = 0; j < NSTRIP; ++j) {
        const float2 pp = partials[lane * NSTRIP + j];
        s0 += pp.x; s1 += pp.y;
    }
    float q = s1 / s0;
    q = wave_reduce(q);
    if (lane == 0) out[0] = q * (1.0f / (float)BATCH);
}

extern "C" void kernel_launch(void* const* d_in, const int* in_sizes, int n_in,
                              void* d_out, int out_size, void* d_ws, size_t ws_size,
                              hipStream_t stream) {
    const float* pred = (const float*)d_in[0];
    const float* mask = (const float*)d_in[1];
    float2* partials = (float2*)d_ws;   // 512 * 8B

    hipLaunchKernelGGL(fused_kernel, dim3(BATCH * NSTRIP), dim3(512), 0, stream,
                       pred, mask, partials);
    hipLaunchKernelGGL(finalize_kernel, dim3(1), dim3(64), 0, stream,
                       partials, (float*)d_out);
}